// Round 4
// baseline (122.574 us; speedup 1.0000x reference)
//
#include <hip/hip_runtime.h>
#include <cstdint>
#include <climits>

#define EPSF 1e-7f
#define NCELL 1000          // 10x10x10 cells per batch, cell size 0.1 = radius
#define RPAD 0.10002f       // radius + fuzz for f32 binning boundary safety

// SESSION LESSONS (measured):
//  - R2(prev): __threadfence per-wave = cache-wide buffer_wbl2 -> +300us.
//  - R6(prev): same-address device atomics from 16k waves serialize -> +70us.
//  - R10/R11(prev): block-level LDS retirement best for k3.
//  - This session R1: k1 3x-fewer-loads neutral -> k1 tiny / not load-bound.
//  - This session R2: k3 VGPR diet + launch_bounds(256,8) neutral (normalized
//    by fill-time: container was ~5% slower) -> k3 not occupancy-capped.
//  - Roofline arithmetic: total touched data ~2MB, kernel work sums to
//    ~20-25us vs 101us measured -> overhead/serialization theory.
//  - THIS ROUND: 5 nodes -> 3. K12 = k1+k2 fused via co-resident spin
//    (56 blocks, deadlock-free by residency). k3 absorbs k4 via 64 atomic
//    buckets + ticket, and normalizes vertex normals inline (vert[] deleted).

__device__ __forceinline__ int cell_of(float x, float y, float z) {
    int cx = min(max((int)(x * 10.0f), 0), 9);
    int cy = min(max((int)(y * 10.0f), 0), 9);
    int cz = min(max((int)(z * 10.0f), 0), 9);
    return (cx * 10 + cy) * 10 + cz;
}

// ---------------------------------------------------------------------------
// K12: fused build. Blocks [0, nfb): per-face normal atomics + vertex cell
// histogram. Blocks [nfb, nfb+bs): spin until face blocks done, then
// per-batch scan + scatter. All nfb+bs (=56) blocks are co-resident on 256
// CUs, so the spin cannot deadlock under any dispatch order.
// ---------------------------------------------------------------------------
__global__ void k12_build(const float* __restrict__ hs,
                          const int* __restrict__ hf,
                          float* __restrict__ svec,
                          float* __restrict__ scnt,
                          int* __restrict__ counts,
                          int* __restrict__ ctrl,
                          int* __restrict__ cellstart,
                          float4* __restrict__ spk,
                          int n_v, int n_f, int bs, int nfb) {
    __shared__ int cursor_l[NCELL];
    const int blk = blockIdx.x;

    if (blk < nfb) {
        // ---- face-normal accumulation + histogram (old k1) ----
        int t = blk * blockDim.x + threadIdx.x;
        if (t < bs * n_f) {
            int b = t / n_f;
            int f = t - b * n_f;
            const int* fb = hf + (size_t)b * 3 * n_f;
            int i0 = fb[f];
            int i1 = fb[n_f + f];
            int i2 = fb[2 * n_f + f];
            const float* xs = hs + (size_t)b * 6 * n_v;
            const float* ys = xs + n_v;
            const float* zs = xs + 2 * n_v;
            float ax = xs[i0], ay = ys[i0], az = zs[i0];
            float bx = xs[i1], by = ys[i1], bz = zs[i1];
            float cx = xs[i2], cy = ys[i2], cz = zs[i2];
            float e1x = bx - ax, e1y = by - ay, e1z = bz - az;
            float e2x = cx - ax, e2y = cy - ay, e2z = cz - az;
            float fx = e1y * e2z - e1z * e2y;
            float fy = e1z * e2x - e1x * e2z;
            float fz = e1x * e2y - e1y * e2x;
            float nrm = sqrtf(fx * fx + fy * fy + fz * fz) + EPSF;
            fx /= nrm; fy /= nrm; fz /= nrm;
            float* sb = svec + (size_t)b * n_v * 3;
            float* cb = scnt + (size_t)b * n_v;
            atomicAdd(&sb[i0 * 3 + 0], fx);
            atomicAdd(&sb[i0 * 3 + 1], fy);
            atomicAdd(&sb[i0 * 3 + 2], fz);
            atomicAdd(&sb[i1 * 3 + 0], fx);
            atomicAdd(&sb[i1 * 3 + 1], fy);
            atomicAdd(&sb[i1 * 3 + 2], fz);
            atomicAdd(&sb[i2 * 3 + 0], fx);
            atomicAdd(&sb[i2 * 3 + 1], fy);
            atomicAdd(&sb[i2 * 3 + 2], fz);
            atomicAdd(&cb[i0], 1.0f);
            atomicAdd(&cb[i1], 1.0f);
            atomicAdd(&cb[i2], 1.0f);
        }
        if (t < bs * n_v) {
            int b = t / n_v;
            int v = t - b * n_v;
            const float* xs = hs + (size_t)b * 6 * n_v;
            float x = xs[v], y = xs[n_v + v], z = xs[2 * n_v + v];
            atomicAdd(&counts[b * NCELL + cell_of(x, y, z)], 1);
        }
        // __syncthreads drains each wave's vmcnt -> all this block's atomics
        // are complete at TCC before the ticket below.
        __syncthreads();
        if (threadIdx.x == 0) atomicAdd(&ctrl[0], 1);
        return;
    }

    // ---- scan + scatter (old k2 batch part) ----
    const int batch = blk - nfb;
    if (threadIdx.x == 0) {
        while (atomicAdd(&ctrl[0], 0) < nfb) { /* spin */ }
    }
    __syncthreads();

    if (threadIdx.x < 64) {
        int lane = threadIdx.x;
        int local[16];
        int mysum = 0;
        #pragma unroll
        for (int k = 0; k < 16; ++k) {
            int c = lane * 16 + k;
            int v = (c < NCELL) ? counts[batch * NCELL + c] : 0;
            local[k] = v;
            mysum += v;
        }
        int s = mysum;
        #pragma unroll
        for (int off = 1; off < 64; off <<= 1) {
            int n = __shfl_up(s, off);
            if (lane >= off) s += n;
        }
        int excl = s - mysum;
        #pragma unroll
        for (int k = 0; k < 16; ++k) {
            int c = lane * 16 + k;
            if (c < NCELL) {
                cellstart[batch * (NCELL + 1) + c] = excl;
                cursor_l[c] = excl;
                excl += local[k];
            }
        }
        if (lane == 63) cellstart[batch * (NCELL + 1) + NCELL] = s;
    }
    __syncthreads();
    const float* xs = hs + (size_t)batch * 6 * n_v;
    for (int v = threadIdx.x; v < n_v; v += blockDim.x) {
        float x = xs[v], y = xs[n_v + v], z = xs[2 * n_v + v];
        int cell = cell_of(x, y, z);
        int pos = atomicAdd(&cursor_l[cell], 1);
        spk[(size_t)batch * n_v + pos] = make_float4(x, y, z, __int_as_float(v));
    }
}

// ---------------------------------------------------------------------------
// K3F: half-wave queries (one query per 32 lanes) + eager round-0 loads +
// inline lazy vertex-normal normalize (vert[] deleted) + in-kernel final
// reduction via 64 atomic buckets + ticket (k4 deleted).
// ---------------------------------------------------------------------------
__global__ void k3_query(const float* __restrict__ pred,
                         const float* __restrict__ hs,
                         const float* __restrict__ svec,
                         const float* __restrict__ scnt,
                         const float4* __restrict__ spk,
                         const int* __restrict__ cellstart,
                         double* __restrict__ gsum,
                         float* __restrict__ gcnt,
                         int* __restrict__ ctrl,
                         float* __restrict__ out,
                         int n_v, int n_pred, int bs) {
    const int lane = threadIdx.x & 63;
    const int wave = threadIdx.x >> 6;
    const int sub = lane & 31;          // lane within half-wave
    const int half = lane >> 5;
    const int qid = blockIdx.x * 8 + wave * 2 + half;
    const int nq = bs * n_pred;

    float per_pt = 0.0f;
    float is_pos = 0.0f;

    if (qid < nq) {
        const int b = qid / n_pred;
        const float4* sp = spk + (size_t)b * n_v;
        const int* csb = cellstart + b * (NCELL + 1);
        const float px = pred[(size_t)qid * 3 + 0];
        const float py = pred[(size_t)qid * 3 + 1];
        const float pz = pred[(size_t)qid * 3 + 2];

        int xlo = max(0, (int)floorf((px - RPAD) * 10.0f));
        int xhi = min(9, (int)floorf((px + RPAD) * 10.0f));
        int ylo = max(0, (int)floorf((py - RPAD) * 10.0f));
        int yhi = min(9, (int)floorf((py + RPAD) * 10.0f));
        int zlo = max(0, (int)floorf((pz - RPAD) * 10.0f));
        int zhi = min(9, (int)floorf((pz + RPAD) * 10.0f));

        int ip = min(sub, 8);
        int cxr = xlo + ip / 3;
        int cyr = ylo + ip % 3;
        bool validr = (cxr <= xhi) && (cyr <= yhi) && (sub < 9);
        int rowbase = (min(cxr, 9) * 10 + min(cyr, 9)) * 10;
        int rsv = csb[rowbase + zlo];
        int rev = csb[rowbase + zhi + 1];
        if (!validr) rev = rsv;         // empty run

        // Packed run bounds: RE in high 16 bits, RS in low 16 (both < 6891).
        unsigned PK[9];
        #pragma unroll
        for (int i = 0; i < 9; ++i) {
            unsigned rs = (unsigned)__shfl(rsv, i, 32);
            unsigned re = (unsigned)__shfl(rev, i, 32);
            PK[i] = (re << 16) | rs;
        }

        float4 c0[9];
        #pragma unroll
        for (int i = 0; i < 9; ++i) {
            int p = (int)(PK[i] & 0xffffu) + sub;
            c0[i] = sp[(p < (int)(PK[i] >> 16)) ? p : 0];
        }

        int l0 = INT_MAX, l1 = INT_MAX, l2 = INT_MAX, l3 = INT_MAX;
        #pragma unroll
        for (int i = 0; i < 9; ++i) {
            if ((int)(PK[i] & 0xffffu) + sub < (int)(PK[i] >> 16)) {
                float4 c4 = c0[i];
                float dx = px - c4.x;
                float dy = py - c4.y;
                float dz = pz - c4.z;
                float d2 = dx * dx + dy * dy + dz * dz;
                if (d2 < 0.01f) {           // 0.01f == f32(0.1*0.1)
                    int vid = __float_as_int(c4.w);
                    if (vid < l3) {
                        if (vid < l1) {
                            if (vid < l0) { l3 = l2; l2 = l1; l1 = l0; l0 = vid; }
                            else          { l3 = l2; l2 = l1; l1 = vid; }
                        } else {
                            if (vid < l2) { l3 = l2; l2 = vid; }
                            else          { l3 = vid; }
                        }
                    }
                }
            }
        }
        #pragma unroll
        for (int i = 0; i < 9; ++i) {
            int re = (int)(PK[i] >> 16);
            for (int p = (int)(PK[i] & 0xffffu) + 32 + sub; p < re; p += 32) {
                float4 c4 = sp[p];
                float dx = px - c4.x;
                float dy = py - c4.y;
                float dz = pz - c4.z;
                float d2 = dx * dx + dy * dy + dz * dz;
                if (d2 < 0.01f) {
                    int vid = __float_as_int(c4.w);
                    if (vid < l3) {
                        if (vid < l1) {
                            if (vid < l0) { l3 = l2; l2 = l1; l1 = l0; l0 = vid; }
                            else          { l3 = l2; l2 = l1; l1 = vid; }
                        } else {
                            if (vid < l2) { l3 = l2; l2 = vid; }
                            else          { l3 = vid; }
                        }
                    }
                }
            }
        }

        #pragma unroll
        for (int off = 1; off < 32; off <<= 1) {
            int r0 = __shfl_xor(l3, off);
            int r1 = __shfl_xor(l2, off);
            int r2 = __shfl_xor(l1, off);
            int r3 = __shfl_xor(l0, off);
            int m0 = min(l0, r0);
            int m1 = min(l1, r1);
            int m2 = min(l2, r2);
            int m3 = min(l3, r3);
            int t0 = min(m0, m2), t2 = max(m0, m2);
            int t1 = min(m1, m3), t3 = max(m1, m3);
            l0 = min(t0, t1); l1 = max(t0, t1);
            l2 = min(t2, t3); l3 = max(t2, t3);
        }

        int id0 = (l0 == INT_MAX) ? 0 : l0;      // no hits -> index 0
        int id1 = (l1 == INT_MAX) ? id0 : l1;    // unfilled -> first hit
        int id2 = (l2 == INT_MAX) ? id0 : l2;
        int id3 = (l3 == INT_MAX) ? id0 : l3;
        int ids[4] = {id0, id1, id2, id3};

        // lazy vertex-normal: same ops/order as old k2 normalize -> same bits
        const float* xs = hs + (size_t)b * 6 * n_v;
        const float* ysv = xs + n_v;
        const float* zsv = xs + 2 * n_v;
        const float* svb = svec + (size_t)b * n_v * 3;
        const float* scb = scnt + (size_t)b * n_v;

        float vd[4];
        float cm = 0.0f;
        #pragma unroll
        for (int j = 0; j < 4; ++j) {
            int id = ids[j];
            float cc = scb[id] + EPSF;
            float vx = svb[id * 3 + 0] / cc;
            float vy = svb[id * 3 + 1] / cc;
            float vz = svb[id * 3 + 2] / cc;
            float nrm = sqrtf(vx * vx + vy * vy + vz * vz) + EPSF;
            float njx = vx / nrm, njy = vy / nrm, njz = vz / nrm;
            float dx = px - xs[id];
            float dy = py - ysv[id];
            float dz = pz - zsv[id];
            float dot = dx * njx + dy * njy + dz * njz;
            float w = (dot >= -0.1f) ? 1.0f : 0.0f;
            float v = (dot - 0.001f) * w;
            bool msk = v < 0.0f;
            vd[j] = msk ? v : 0.0f;
            cm += msk ? 1.0f : 0.0f;
        }
        float s = ((vd[0] + vd[1]) + vd[2]) + vd[3];
        float a = s / (cm + EPSF);
        per_pt = a * a;
        is_pos = (per_pt > 0.0f) ? 1.0f : 0.0f;
    }

    __shared__ float ls[8];
    __shared__ float lc[8];
    __shared__ int lastflag;
    if (sub == 0) {
        int slot = wave * 2 + half;
        ls[slot] = per_pt;
        lc[slot] = is_pos;
    }
    __syncthreads();
    if (threadIdx.x == 0) {
        double ssum = 0.0;
        float csum = 0.0f;
        #pragma unroll
        for (int k = 0; k < 8; ++k) {
            ssum += (double)ls[k];
            csum += lc[k];
        }
        double o1 = atomicAdd(&gsum[blockIdx.x & 63], ssum);
        float  o2 = atomicAdd(&gcnt[blockIdx.x & 63], csum);
        // Force vmcnt-wait on the bucket RMWs before the ticket RMW so the
        // last block observing ticket==grid-1 implies all buckets complete.
        float oo = (float)o1 + o2;
        asm volatile("" : : "v"(oo) : "memory");
        int old = atomicAdd(&ctrl[1], 1);
        lastflag = (old == (int)gridDim.x - 1) ? 1 : 0;
    }
    __syncthreads();
    if (lastflag) {
        if (threadIdx.x < 64) {
            double s = atomicAdd(&gsum[threadIdx.x], 0.0);   // coherent read
            double c = (double)atomicAdd(&gcnt[threadIdx.x], 0.0f);
            #pragma unroll
            for (int off = 32; off > 0; off >>= 1) {
                s += __shfl_down(s, off);
                c += __shfl_down(c, off);
            }
            if (threadIdx.x == 0) out[0] = (float)(s / (c + 1e-7));
        }
    }
}

extern "C" void kernel_launch(void* const* d_in, const int* in_sizes, int n_in,
                              void* d_out, int out_size, void* d_ws, size_t ws_size,
                              hipStream_t stream) {
    const float* pred    = (const float*)d_in[0];
    const float* h_state = (const float*)d_in[2];
    const int*   h_faces = (const int*)d_in[3];
    float* out = (float*)d_out;

    const int bs = 2;
    const int n_pred = in_sizes[0] / (bs * 3);   // 8192
    const int n_v    = in_sizes[2] / (bs * 6);   // 6890
    const int n_f    = in_sizes[3] / (bs * 3);   // 13776
    const int nq = bs * n_pred;                  // 16384
    const int nblk = (nq + 7) / 8;               // 2048 blocks, 8 queries each
    const int nfb  = (bs * n_f + 511) / 512;     // 54 face blocks @512

    // ---- workspace layout (float-element offsets from d_ws) ----
    size_t o_svec    = 0;                                  // bs*n_v*3 (zeroed)
    size_t o_scnt    = o_svec + (size_t)bs * n_v * 3;      // bs*n_v   (zeroed)
    size_t o_counts  = o_scnt + (size_t)bs * n_v;          // bs*1000 i (zeroed)
    size_t o_ctrl    = o_counts + (size_t)bs * NCELL;      // 2 ints   (zeroed)
    size_t o_gsum    = (o_ctrl + 2 + 1) & ~(size_t)1;      // 64 doubles (zeroed)
    size_t o_gcnt    = o_gsum + 2 * 64;                    // 64 floats  (zeroed)
    size_t o_zeroend = (o_gcnt + 64 + 3) & ~(size_t)3;
    size_t o_cs      = o_zeroend;                          // bs*1001 i
    size_t o_spk     = (o_cs + (size_t)bs * (NCELL + 1) + 3) & ~(size_t)3; // bs*n_v f4

    float* base = (float*)d_ws;
    float*  svec      = base + o_svec;
    float*  scnt      = base + o_scnt;
    int*    counts    = (int*)(base + o_counts);
    int*    ctrl      = (int*)(base + o_ctrl);
    double* gsum      = (double*)(base + o_gsum);
    float*  gcnt      = base + o_gcnt;
    int*    cellstart = (int*)(base + o_cs);
    float4* spk       = (float4*)(base + o_spk);

    hipMemsetAsync(d_ws, 0, o_zeroend * sizeof(float), stream);

    k12_build<<<nfb + bs, 512, 0, stream>>>(
        h_state, h_faces, svec, scnt, counts, ctrl, cellstart, spk,
        n_v, n_f, bs, nfb);

    k3_query<<<nblk, 256, 0, stream>>>(
        pred, h_state, svec, scnt, spk, cellstart, gsum, gcnt, ctrl, out,
        n_v, n_pred, bs);
}

// Round 5
// 112.004 us; speedup vs baseline: 1.0944x; 1.0944x over previous
//
#include <hip/hip_runtime.h>
#include <cstdint>
#include <climits>

#define EPSF 1e-7f
#define NCELL 1000          // 10x10x10 cells per batch, cell size 0.1 = radius
#define RPAD 0.10002f       // radius + fuzz for f32 binning boundary safety

// SESSION LESSONS (measured):
//  - prevR2: per-wave __threadfence = cache-wide wb -> +300us. Never fence.
//  - prevR6: same-address device atomics serialize cross-XCD (16k -> +70us).
//  - prevR10/R11: k3 block-level LDS retirement is best; per-wave costs ~7us.
//  - R1: k1 3x-fewer-loads neutral -> k1 tiny.
//  - R2: k3 VGPR diet + launch_bounds neutral -> k3 not occupancy-capped.
//  - R3: spin-fusion + 2048-ticket + bucket tail = +21.5us REGRESSION.
//    Ticket/bucket same-address RMWs are the prime suspect (R6 pattern).
//  - Model: ~80us of timed poison fills + ~21us attackable kernel time.
//  - THIS ROUND: 5 -> 4 nodes with ORDER-FREE fusion only. Scanner blocks
//    build their own LDS histogram (drops counts[] dependency on k1), so
//    faces-atomics and hist/scan/scatter share one kernel with NO sync.
//    k3 normalizes vertex normals lazily (bit-identical math, proven R3).
//    No spins, no tickets, no new atomics. k3 tail + k4 = R2's measured best.

__device__ __forceinline__ int cell_of(float x, float y, float z) {
    int cx = min(max((int)(x * 10.0f), 0), 9);
    int cy = min(max((int)(y * 10.0f), 0), 9);
    int cz = min(max((int)(z * 10.0f), 0), 9);
    return (cx * 10 + cy) * 10 + cz;
}

// ---------------------------------------------------------------------------
// K_AB: blocks [0,nfb): per-face normal atomics into svec/scnt.
//       blocks [nfb, nfb+bs): per-batch LDS histogram -> scan -> scatter.
// The two groups touch disjoint outputs and neither reads the other's
// writes -> no ordering, no spin, safe under any dispatch order.
// ---------------------------------------------------------------------------
__global__ void k_ab(const float* __restrict__ hs,
                     const int* __restrict__ hf,
                     float* __restrict__ svec,
                     float* __restrict__ scnt,
                     int* __restrict__ cellstart,
                     float4* __restrict__ spk,
                     int n_v, int n_f, int bs, int nfb) {
    __shared__ int hist[NCELL];
    const int blk = blockIdx.x;

    if (blk < nfb) {
        // ---- face-normal accumulation (old k1, minus histogram) ----
        int t = blk * blockDim.x + threadIdx.x;
        if (t < bs * n_f) {
            int b = t / n_f;
            int f = t - b * n_f;
            const int* fb = hf + (size_t)b * 3 * n_f;
            int i0 = fb[f];
            int i1 = fb[n_f + f];
            int i2 = fb[2 * n_f + f];
            const float* xs = hs + (size_t)b * 6 * n_v;
            const float* ys = xs + n_v;
            const float* zs = xs + 2 * n_v;
            float ax = xs[i0], ay = ys[i0], az = zs[i0];
            float bx = xs[i1], by = ys[i1], bz = zs[i1];
            float cx = xs[i2], cy = ys[i2], cz = zs[i2];
            float e1x = bx - ax, e1y = by - ay, e1z = bz - az;
            float e2x = cx - ax, e2y = cy - ay, e2z = cz - az;
            float fx = e1y * e2z - e1z * e2y;
            float fy = e1z * e2x - e1x * e2z;
            float fz = e1x * e2y - e1y * e2x;
            float nrm = sqrtf(fx * fx + fy * fy + fz * fz) + EPSF;
            fx /= nrm; fy /= nrm; fz /= nrm;
            float* sb = svec + (size_t)b * n_v * 3;
            float* cb = scnt + (size_t)b * n_v;
            atomicAdd(&sb[i0 * 3 + 0], fx);
            atomicAdd(&sb[i0 * 3 + 1], fy);
            atomicAdd(&sb[i0 * 3 + 2], fz);
            atomicAdd(&sb[i1 * 3 + 0], fx);
            atomicAdd(&sb[i1 * 3 + 1], fy);
            atomicAdd(&sb[i1 * 3 + 2], fz);
            atomicAdd(&sb[i2 * 3 + 0], fx);
            atomicAdd(&sb[i2 * 3 + 1], fy);
            atomicAdd(&sb[i2 * 3 + 2], fz);
            atomicAdd(&cb[i0], 1.0f);
            atomicAdd(&cb[i1], 1.0f);
            atomicAdd(&cb[i2], 1.0f);
        }
        return;
    }

    // ---- per-batch self-contained hist + scan + scatter ----
    const int batch = blk - nfb;
    const float* xs = hs + (size_t)batch * 6 * n_v;

    for (int c = threadIdx.x; c < NCELL; c += blockDim.x) hist[c] = 0;
    __syncthreads();
    for (int v = threadIdx.x; v < n_v; v += blockDim.x) {
        float x = xs[v], y = xs[n_v + v], z = xs[2 * n_v + v];
        atomicAdd(&hist[cell_of(x, y, z)], 1);
    }
    __syncthreads();

    if (threadIdx.x < 64) {
        int lane = threadIdx.x;
        int local[16];
        int mysum = 0;
        #pragma unroll
        for (int k = 0; k < 16; ++k) {
            int c = lane * 16 + k;
            int v = (c < NCELL) ? hist[c] : 0;
            local[k] = v;
            mysum += v;
        }
        int s = mysum;
        #pragma unroll
        for (int off = 1; off < 64; off <<= 1) {
            int n = __shfl_up(s, off);
            if (lane >= off) s += n;
        }
        int excl = s - mysum;
        #pragma unroll
        for (int k = 0; k < 16; ++k) {
            int c = lane * 16 + k;
            if (c < NCELL) {
                cellstart[batch * (NCELL + 1) + c] = excl;
                hist[c] = excl;                    // becomes scatter cursor
                excl += local[k];
            }
        }
        if (lane == 63) cellstart[batch * (NCELL + 1) + NCELL] = s;
    }
    __syncthreads();

    for (int v = threadIdx.x; v < n_v; v += blockDim.x) {
        float x = xs[v], y = xs[n_v + v], z = xs[2 * n_v + v];
        int cell = cell_of(x, y, z);
        int pos = atomicAdd(&hist[cell], 1);
        spk[(size_t)batch * n_v + pos] = make_float4(x, y, z, __int_as_float(v));
    }
}

// ---------------------------------------------------------------------------
// K3: half-wave queries (one query per 32 lanes, 8192 waves) + eager
// round-0 candidate loads + lazy vertex-normal normalize (bit-identical to
// old k2's math) + BLOCK-LEVEL LDS retirement into partial[] (measured best).
// ---------------------------------------------------------------------------
__global__ __launch_bounds__(256, 8) void k3_query(
                         const float* __restrict__ pred,
                         const float* __restrict__ hs,
                         const float* __restrict__ svec,
                         const float* __restrict__ scnt,
                         const float4* __restrict__ spk,
                         const int* __restrict__ cellstart,
                         double* __restrict__ partial,
                         float* __restrict__ pcnt,
                         int n_v, int n_pred, int bs) {
    const int lane = threadIdx.x & 63;
    const int wave = threadIdx.x >> 6;
    const int sub = lane & 31;          // lane within half-wave
    const int half = lane >> 5;
    const int qid = blockIdx.x * 8 + wave * 2 + half;
    const int nq = bs * n_pred;

    float per_pt = 0.0f;
    float is_pos = 0.0f;

    if (qid < nq) {
        const int b = qid / n_pred;
        const float4* sp = spk + (size_t)b * n_v;
        const int* csb = cellstart + b * (NCELL + 1);
        const float px = pred[(size_t)qid * 3 + 0];
        const float py = pred[(size_t)qid * 3 + 1];
        const float pz = pred[(size_t)qid * 3 + 2];

        int xlo = max(0, (int)floorf((px - RPAD) * 10.0f));
        int xhi = min(9, (int)floorf((px + RPAD) * 10.0f));
        int ylo = max(0, (int)floorf((py - RPAD) * 10.0f));
        int yhi = min(9, (int)floorf((py + RPAD) * 10.0f));
        int zlo = max(0, (int)floorf((pz - RPAD) * 10.0f));
        int zhi = min(9, (int)floorf((pz + RPAD) * 10.0f));

        int ip = min(sub, 8);
        int cxr = xlo + ip / 3;
        int cyr = ylo + ip % 3;
        bool validr = (cxr <= xhi) && (cyr <= yhi) && (sub < 9);
        int rowbase = (min(cxr, 9) * 10 + min(cyr, 9)) * 10;
        int rsv = csb[rowbase + zlo];
        int rev = csb[rowbase + zhi + 1];
        if (!validr) rev = rsv;         // empty run

        // Packed run bounds: RE in high 16 bits, RS in low 16 (both < 6891).
        unsigned PK[9];
        #pragma unroll
        for (int i = 0; i < 9; ++i) {
            unsigned rs = (unsigned)__shfl(rsv, i, 32);
            unsigned re = (unsigned)__shfl(rev, i, 32);
            PK[i] = (re << 16) | rs;
        }

        float4 c0[9];
        #pragma unroll
        for (int i = 0; i < 9; ++i) {
            int p = (int)(PK[i] & 0xffffu) + sub;
            c0[i] = sp[(p < (int)(PK[i] >> 16)) ? p : 0];
        }

        int l0 = INT_MAX, l1 = INT_MAX, l2 = INT_MAX, l3 = INT_MAX;
        #pragma unroll
        for (int i = 0; i < 9; ++i) {
            if ((int)(PK[i] & 0xffffu) + sub < (int)(PK[i] >> 16)) {
                float4 c4 = c0[i];
                float dx = px - c4.x;
                float dy = py - c4.y;
                float dz = pz - c4.z;
                float d2 = dx * dx + dy * dy + dz * dz;
                if (d2 < 0.01f) {           // 0.01f == f32(0.1*0.1)
                    int vid = __float_as_int(c4.w);
                    if (vid < l3) {
                        if (vid < l1) {
                            if (vid < l0) { l3 = l2; l2 = l1; l1 = l0; l0 = vid; }
                            else          { l3 = l2; l2 = l1; l1 = vid; }
                        } else {
                            if (vid < l2) { l3 = l2; l2 = vid; }
                            else          { l3 = vid; }
                        }
                    }
                }
            }
        }
        #pragma unroll
        for (int i = 0; i < 9; ++i) {
            int re = (int)(PK[i] >> 16);
            for (int p = (int)(PK[i] & 0xffffu) + 32 + sub; p < re; p += 32) {
                float4 c4 = sp[p];
                float dx = px - c4.x;
                float dy = py - c4.y;
                float dz = pz - c4.z;
                float d2 = dx * dx + dy * dy + dz * dz;
                if (d2 < 0.01f) {
                    int vid = __float_as_int(c4.w);
                    if (vid < l3) {
                        if (vid < l1) {
                            if (vid < l0) { l3 = l2; l2 = l1; l1 = l0; l0 = vid; }
                            else          { l3 = l2; l2 = l1; l1 = vid; }
                        } else {
                            if (vid < l2) { l3 = l2; l2 = vid; }
                            else          { l3 = vid; }
                        }
                    }
                }
            }
        }

        #pragma unroll
        for (int off = 1; off < 32; off <<= 1) {
            int r0 = __shfl_xor(l3, off);
            int r1 = __shfl_xor(l2, off);
            int r2 = __shfl_xor(l1, off);
            int r3 = __shfl_xor(l0, off);
            int m0 = min(l0, r0);
            int m1 = min(l1, r1);
            int m2 = min(l2, r2);
            int m3 = min(l3, r3);
            int t0 = min(m0, m2), t2 = max(m0, m2);
            int t1 = min(m1, m3), t3 = max(m1, m3);
            l0 = min(t0, t1); l1 = max(t0, t1);
            l2 = min(t2, t3); l3 = max(t2, t3);
        }

        int id0 = (l0 == INT_MAX) ? 0 : l0;      // no hits -> index 0
        int id1 = (l1 == INT_MAX) ? id0 : l1;    // unfilled -> first hit
        int id2 = (l2 == INT_MAX) ? id0 : l2;
        int id3 = (l3 == INT_MAX) ? id0 : l3;
        int ids[4] = {id0, id1, id2, id3};

        // lazy vertex-normal: same ops/order as old k2 normalize -> same bits
        const float* xs = hs + (size_t)b * 6 * n_v;
        const float* ysv = xs + n_v;
        const float* zsv = xs + 2 * n_v;
        const float* svb = svec + (size_t)b * n_v * 3;
        const float* scb = scnt + (size_t)b * n_v;

        float vd[4];
        float cm = 0.0f;
        #pragma unroll
        for (int j = 0; j < 4; ++j) {
            int id = ids[j];
            float cc = scb[id] + EPSF;
            float vx = svb[id * 3 + 0] / cc;
            float vy = svb[id * 3 + 1] / cc;
            float vz = svb[id * 3 + 2] / cc;
            float nrm = sqrtf(vx * vx + vy * vy + vz * vz) + EPSF;
            float njx = vx / nrm, njy = vy / nrm, njz = vz / nrm;
            float dx = px - xs[id];
            float dy = py - ysv[id];
            float dz = pz - zsv[id];
            float dot = dx * njx + dy * njy + dz * njz;
            float w = (dot >= -0.1f) ? 1.0f : 0.0f;
            float v = (dot - 0.001f) * w;
            bool msk = v < 0.0f;
            vd[j] = msk ? v : 0.0f;
            cm += msk ? 1.0f : 0.0f;
        }
        float s = ((vd[0] + vd[1]) + vd[2]) + vd[3];
        float a = s / (cm + EPSF);
        per_pt = a * a;
        is_pos = (per_pt > 0.0f) ? 1.0f : 0.0f;
    }

    __shared__ float ls[8];
    __shared__ float lc[8];
    if (sub == 0) {
        int slot = wave * 2 + half;
        ls[slot] = per_pt;
        lc[slot] = is_pos;
    }
    __syncthreads();
    if (threadIdx.x == 0) {
        double ssum = 0.0;
        float csum = 0.0f;
        #pragma unroll
        for (int k = 0; k < 8; ++k) {
            ssum += (double)ls[k];
            csum += lc[k];
        }
        partial[blockIdx.x] = ssum;     // distinct address per block
        pcnt[blockIdx.x] = csum;
    }
}

// ---------------------------------------------------------------------------
// K4: single-block reduction of the block partials -> final scalar loss.
// ---------------------------------------------------------------------------
__global__ void finalize_kernel(const double* __restrict__ partial,
                                const float* __restrict__ pcnt,
                                int n, float* __restrict__ out) {
    double s = 0.0, c = 0.0;
    for (int i = threadIdx.x; i < n; i += blockDim.x) {
        s += partial[i];
        c += (double)pcnt[i];
    }
    #pragma unroll
    for (int off = 32; off > 0; off >>= 1) {
        s += __shfl_down(s, off);
        c += __shfl_down(c, off);
    }
    __shared__ double ws_s[4];
    __shared__ double ws_c[4];
    int wave = threadIdx.x >> 6;
    int lane = threadIdx.x & 63;
    if (lane == 0) { ws_s[wave] = s; ws_c[wave] = c; }
    __syncthreads();
    if (threadIdx.x == 0) {
        double S = ws_s[0] + ws_s[1] + ws_s[2] + ws_s[3];
        double C = ws_c[0] + ws_c[1] + ws_c[2] + ws_c[3];
        out[0] = (float)(S / (C + 1e-7));
    }
}

extern "C" void kernel_launch(void* const* d_in, const int* in_sizes, int n_in,
                              void* d_out, int out_size, void* d_ws, size_t ws_size,
                              hipStream_t stream) {
    const float* pred    = (const float*)d_in[0];
    const float* h_state = (const float*)d_in[2];
    const int*   h_faces = (const int*)d_in[3];
    float* out = (float*)d_out;

    const int bs = 2;
    const int n_pred = in_sizes[0] / (bs * 3);   // 8192
    const int n_v    = in_sizes[2] / (bs * 6);   // 6890
    const int n_f    = in_sizes[3] / (bs * 3);   // 13776
    const int nq = bs * n_pred;                  // 16384
    const int nblk = (nq + 7) / 8;               // 2048 blocks, 8 queries each
    const int nfb  = (bs * n_f + 1023) / 1024;   // 27 face blocks @1024

    // ---- workspace layout (float-element offsets from d_ws) ----
    size_t o_svec    = 0;                                  // bs*n_v*3 (zeroed)
    size_t o_scnt    = o_svec + (size_t)bs * n_v * 3;      // bs*n_v   (zeroed)
    size_t o_zeroend = (o_scnt + (size_t)bs * n_v + 3) & ~(size_t)3;
    size_t o_cs      = o_zeroend;                          // bs*1001 i
    size_t o_partial = (o_cs + (size_t)bs * (NCELL + 1) + 1) & ~(size_t)1; // nblk d
    size_t o_pcnt    = o_partial + 2 * (size_t)nblk;       // nblk f
    size_t o_spk     = (o_pcnt + (size_t)nblk + 3) & ~(size_t)3;   // bs*n_v f4

    float* base = (float*)d_ws;
    float*  svec      = base + o_svec;
    float*  scnt      = base + o_scnt;
    int*    cellstart = (int*)(base + o_cs);
    double* partial   = (double*)(base + o_partial);
    float*  pcnt      = base + o_pcnt;
    float4* spk       = (float4*)(base + o_spk);

    hipMemsetAsync(d_ws, 0, o_zeroend * sizeof(float), stream);

    k_ab<<<nfb + bs, 1024, 0, stream>>>(
        h_state, h_faces, svec, scnt, cellstart, spk, n_v, n_f, bs, nfb);

    k3_query<<<nblk, 256, 0, stream>>>(
        pred, h_state, svec, scnt, spk, cellstart, partial, pcnt,
        n_v, n_pred, bs);

    finalize_kernel<<<1, 256, 0, stream>>>(partial, pcnt, nblk, out);
}

// Round 7
// 109.788 us; speedup vs baseline: 1.1165x; 1.0202x over previous
//
#include <hip/hip_runtime.h>
#include <cstdint>
#include <climits>

#define EPSF 1e-7f
#define NCELL 1000          // 10x10x10 cells per batch, cell size 0.1 = radius
#define RPAD 0.10002f       // radius + fuzz for f32 binning boundary safety

// SESSION LESSONS (measured):
//  - prevR2: per-wave __threadfence = cache-wide wb -> +300us. Never fence.
//  - prevR6: same-address device atomics serialize cross-XCD (16k -> +70us).
//  - prevR10/R11: k3 block-level LDS retirement is best; per-wave costs ~7us.
//  - R1: k1 3x-fewer-loads neutral -> k1 tiny.
//  - R2: k3 VGPR diet + launch_bounds neutral -> k3 not occupancy-capped.
//  - R3: spin-fusion + 2048-ticket + bucket tail = +21.5us. Decomposed via
//    R4: ticket/bucket ~ +18us (R6 pattern), lazy normals ~ +3.5us.
//  - R4: order-free k1+k2 fusion is ~NEUTRAL; lazy normals regress (+3.5us):
//    8 scattered scalar loads/neighbor vs 2 coherent float4 from vert[].
//  - Model: ~80us of timed poison fills + ~21us attackable kernel time.
//  - R5: revert lazy normals (restore vert[] + vb gather = verified R2 k3),
//    keep order-free fusion. 4 nodes: k_ab, k2n, k3, k4.
//  - THIS ROUND: identical resubmission — R5 bench died to container infra
//    failure; the R5 prediction (normalized ~99-101us) is still untested.

__device__ __forceinline__ int cell_of(float x, float y, float z) {
    int cx = min(max((int)(x * 10.0f), 0), 9);
    int cy = min(max((int)(y * 10.0f), 0), 9);
    int cz = min(max((int)(z * 10.0f), 0), 9);
    return (cx * 10 + cy) * 10 + cz;
}

// ---------------------------------------------------------------------------
// K_AB: blocks [0,nfb): per-face normal atomics into svec/scnt.
//       blocks [nfb, nfb+bs): per-batch LDS histogram -> scan -> scatter.
// Disjoint outputs, no cross-group reads -> safe under any dispatch order.
// ---------------------------------------------------------------------------
__global__ void k_ab(const float* __restrict__ hs,
                     const int* __restrict__ hf,
                     float* __restrict__ svec,
                     float* __restrict__ scnt,
                     int* __restrict__ cellstart,
                     float4* __restrict__ spk,
                     int n_v, int n_f, int bs, int nfb) {
    __shared__ int hist[NCELL];
    const int blk = blockIdx.x;

    if (blk < nfb) {
        // ---- face-normal accumulation ----
        int t = blk * blockDim.x + threadIdx.x;
        if (t < bs * n_f) {
            int b = t / n_f;
            int f = t - b * n_f;
            const int* fb = hf + (size_t)b * 3 * n_f;
            int i0 = fb[f];
            int i1 = fb[n_f + f];
            int i2 = fb[2 * n_f + f];
            const float* xs = hs + (size_t)b * 6 * n_v;
            const float* ys = xs + n_v;
            const float* zs = xs + 2 * n_v;
            float ax = xs[i0], ay = ys[i0], az = zs[i0];
            float bx = xs[i1], by = ys[i1], bz = zs[i1];
            float cx = xs[i2], cy = ys[i2], cz = zs[i2];
            float e1x = bx - ax, e1y = by - ay, e1z = bz - az;
            float e2x = cx - ax, e2y = cy - ay, e2z = cz - az;
            float fx = e1y * e2z - e1z * e2y;
            float fy = e1z * e2x - e1x * e2z;
            float fz = e1x * e2y - e1y * e2x;
            float nrm = sqrtf(fx * fx + fy * fy + fz * fz) + EPSF;
            fx /= nrm; fy /= nrm; fz /= nrm;
            float* sb = svec + (size_t)b * n_v * 3;
            float* cb = scnt + (size_t)b * n_v;
            atomicAdd(&sb[i0 * 3 + 0], fx);
            atomicAdd(&sb[i0 * 3 + 1], fy);
            atomicAdd(&sb[i0 * 3 + 2], fz);
            atomicAdd(&sb[i1 * 3 + 0], fx);
            atomicAdd(&sb[i1 * 3 + 1], fy);
            atomicAdd(&sb[i1 * 3 + 2], fz);
            atomicAdd(&sb[i2 * 3 + 0], fx);
            atomicAdd(&sb[i2 * 3 + 1], fy);
            atomicAdd(&sb[i2 * 3 + 2], fz);
            atomicAdd(&cb[i0], 1.0f);
            atomicAdd(&cb[i1], 1.0f);
            atomicAdd(&cb[i2], 1.0f);
        }
        return;
    }

    // ---- per-batch self-contained hist + scan + scatter ----
    const int batch = blk - nfb;
    const float* xs = hs + (size_t)batch * 6 * n_v;

    for (int c = threadIdx.x; c < NCELL; c += blockDim.x) hist[c] = 0;
    __syncthreads();
    for (int v = threadIdx.x; v < n_v; v += blockDim.x) {
        float x = xs[v], y = xs[n_v + v], z = xs[2 * n_v + v];
        atomicAdd(&hist[cell_of(x, y, z)], 1);
    }
    __syncthreads();

    if (threadIdx.x < 64) {
        int lane = threadIdx.x;
        int local[16];
        int mysum = 0;
        #pragma unroll
        for (int k = 0; k < 16; ++k) {
            int c = lane * 16 + k;
            int v = (c < NCELL) ? hist[c] : 0;
            local[k] = v;
            mysum += v;
        }
        int s = mysum;
        #pragma unroll
        for (int off = 1; off < 64; off <<= 1) {
            int n = __shfl_up(s, off);
            if (lane >= off) s += n;
        }
        int excl = s - mysum;
        #pragma unroll
        for (int k = 0; k < 16; ++k) {
            int c = lane * 16 + k;
            if (c < NCELL) {
                cellstart[batch * (NCELL + 1) + c] = excl;
                hist[c] = excl;                    // becomes scatter cursor
                excl += local[k];
            }
        }
        if (lane == 63) cellstart[batch * (NCELL + 1) + NCELL] = s;
    }
    __syncthreads();

    for (int v = threadIdx.x; v < n_v; v += blockDim.x) {
        float x = xs[v], y = xs[n_v + v], z = xs[2 * n_v + v];
        int cell = cell_of(x, y, z);
        int pos = atomicAdd(&hist[cell], 1);
        spk[(size_t)batch * n_v + pos] = make_float4(x, y, z, __int_as_float(v));
    }
}

// ---------------------------------------------------------------------------
// K2N: normalize svec/scnt -> vert[] (positions + unit normals), the old
// k2 normalize branch as its own small node (14 blocks @1024).
// ---------------------------------------------------------------------------
__global__ void k2_normalize(const float* __restrict__ hs,
                             const float* __restrict__ svec,
                             const float* __restrict__ scnt,
                             float4* __restrict__ vert,
                             int n_v, int bs) {
    int t = blockIdx.x * blockDim.x + threadIdx.x;
    if (t >= bs * n_v) return;
    int b = t / n_v;
    int v = t - b * n_v;
    float cc = scnt[t] + EPSF;
    float vx = svec[t * 3 + 0] / cc;
    float vy = svec[t * 3 + 1] / cc;
    float vz = svec[t * 3 + 2] / cc;
    float nrm = sqrtf(vx * vx + vy * vy + vz * vz) + EPSF;
    const float* xs = hs + (size_t)b * 6 * n_v;
    float x = xs[v], y = xs[n_v + v], z = xs[2 * n_v + v];
    vert[2 * (size_t)t + 0] = make_float4(x, y, z, 0.0f);
    vert[2 * (size_t)t + 1] = make_float4(vx / nrm, vy / nrm, vz / nrm, 0.0f);
}

// ---------------------------------------------------------------------------
// K3: half-wave queries (one query per 32 lanes, 8192 waves) + eager
// round-0 candidate loads + vb[] gather tail + BLOCK-LEVEL LDS retirement
// (the verified R2 configuration, byte-identical math).
// ---------------------------------------------------------------------------
__global__ __launch_bounds__(256, 8) void k3_query(
                         const float* __restrict__ pred,
                         const float4* __restrict__ vert,
                         const float4* __restrict__ spk,
                         const int* __restrict__ cellstart,
                         double* __restrict__ partial,
                         float* __restrict__ pcnt,
                         int n_v, int n_pred, int bs) {
    const int lane = threadIdx.x & 63;
    const int wave = threadIdx.x >> 6;
    const int sub = lane & 31;          // lane within half-wave
    const int half = lane >> 5;
    const int qid = blockIdx.x * 8 + wave * 2 + half;
    const int nq = bs * n_pred;

    float per_pt = 0.0f;
    float is_pos = 0.0f;

    if (qid < nq) {
        const int b = qid / n_pred;
        const float4* vb = vert + 2 * (size_t)b * n_v;
        const float4* sp = spk + (size_t)b * n_v;
        const int* csb = cellstart + b * (NCELL + 1);
        const float px = pred[(size_t)qid * 3 + 0];
        const float py = pred[(size_t)qid * 3 + 1];
        const float pz = pred[(size_t)qid * 3 + 2];

        int xlo = max(0, (int)floorf((px - RPAD) * 10.0f));
        int xhi = min(9, (int)floorf((px + RPAD) * 10.0f));
        int ylo = max(0, (int)floorf((py - RPAD) * 10.0f));
        int yhi = min(9, (int)floorf((py + RPAD) * 10.0f));
        int zlo = max(0, (int)floorf((pz - RPAD) * 10.0f));
        int zhi = min(9, (int)floorf((pz + RPAD) * 10.0f));

        int ip = min(sub, 8);
        int cxr = xlo + ip / 3;
        int cyr = ylo + ip % 3;
        bool validr = (cxr <= xhi) && (cyr <= yhi) && (sub < 9);
        int rowbase = (min(cxr, 9) * 10 + min(cyr, 9)) * 10;
        int rsv = csb[rowbase + zlo];
        int rev = csb[rowbase + zhi + 1];
        if (!validr) rev = rsv;         // empty run

        // Packed run bounds: RE in high 16 bits, RS in low 16 (both < 6891).
        unsigned PK[9];
        #pragma unroll
        for (int i = 0; i < 9; ++i) {
            unsigned rs = (unsigned)__shfl(rsv, i, 32);
            unsigned re = (unsigned)__shfl(rev, i, 32);
            PK[i] = (re << 16) | rs;
        }

        float4 c0[9];
        #pragma unroll
        for (int i = 0; i < 9; ++i) {
            int p = (int)(PK[i] & 0xffffu) + sub;
            c0[i] = sp[(p < (int)(PK[i] >> 16)) ? p : 0];
        }

        int l0 = INT_MAX, l1 = INT_MAX, l2 = INT_MAX, l3 = INT_MAX;
        #pragma unroll
        for (int i = 0; i < 9; ++i) {
            if ((int)(PK[i] & 0xffffu) + sub < (int)(PK[i] >> 16)) {
                float4 c4 = c0[i];
                float dx = px - c4.x;
                float dy = py - c4.y;
                float dz = pz - c4.z;
                float d2 = dx * dx + dy * dy + dz * dz;
                if (d2 < 0.01f) {           // 0.01f == f32(0.1*0.1)
                    int vid = __float_as_int(c4.w);
                    if (vid < l3) {
                        if (vid < l1) {
                            if (vid < l0) { l3 = l2; l2 = l1; l1 = l0; l0 = vid; }
                            else          { l3 = l2; l2 = l1; l1 = vid; }
                        } else {
                            if (vid < l2) { l3 = l2; l2 = vid; }
                            else          { l3 = vid; }
                        }
                    }
                }
            }
        }
        #pragma unroll
        for (int i = 0; i < 9; ++i) {
            int re = (int)(PK[i] >> 16);
            for (int p = (int)(PK[i] & 0xffffu) + 32 + sub; p < re; p += 32) {
                float4 c4 = sp[p];
                float dx = px - c4.x;
                float dy = py - c4.y;
                float dz = pz - c4.z;
                float d2 = dx * dx + dy * dy + dz * dz;
                if (d2 < 0.01f) {
                    int vid = __float_as_int(c4.w);
                    if (vid < l3) {
                        if (vid < l1) {
                            if (vid < l0) { l3 = l2; l2 = l1; l1 = l0; l0 = vid; }
                            else          { l3 = l2; l2 = l1; l1 = vid; }
                        } else {
                            if (vid < l2) { l3 = l2; l2 = vid; }
                            else          { l3 = vid; }
                        }
                    }
                }
            }
        }

        #pragma unroll
        for (int off = 1; off < 32; off <<= 1) {
            int r0 = __shfl_xor(l3, off);
            int r1 = __shfl_xor(l2, off);
            int r2 = __shfl_xor(l1, off);
            int r3 = __shfl_xor(l0, off);
            int m0 = min(l0, r0);
            int m1 = min(l1, r1);
            int m2 = min(l2, r2);
            int m3 = min(l3, r3);
            int t0 = min(m0, m2), t2 = max(m0, m2);
            int t1 = min(m1, m3), t3 = max(m1, m3);
            l0 = min(t0, t1); l1 = max(t0, t1);
            l2 = min(t2, t3); l3 = max(t2, t3);
        }

        int id0 = (l0 == INT_MAX) ? 0 : l0;      // no hits -> index 0
        int id1 = (l1 == INT_MAX) ? id0 : l1;    // unfilled -> first hit
        int id2 = (l2 == INT_MAX) ? id0 : l2;
        int id3 = (l3 == INT_MAX) ? id0 : l3;
        int ids[4] = {id0, id1, id2, id3};

        float vd[4];
        float cm = 0.0f;
        #pragma unroll
        for (int j = 0; j < 4; ++j) {
            int id = ids[j];
            float4 cj = vb[2 * id + 0];
            float4 nj = vb[2 * id + 1];
            float dx = px - cj.x;
            float dy = py - cj.y;
            float dz = pz - cj.z;
            float dot = dx * nj.x + dy * nj.y + dz * nj.z;
            float w = (dot >= -0.1f) ? 1.0f : 0.0f;
            float v = (dot - 0.001f) * w;
            bool msk = v < 0.0f;
            vd[j] = msk ? v : 0.0f;
            cm += msk ? 1.0f : 0.0f;
        }
        float s = ((vd[0] + vd[1]) + vd[2]) + vd[3];
        float a = s / (cm + EPSF);
        per_pt = a * a;
        is_pos = (per_pt > 0.0f) ? 1.0f : 0.0f;
    }

    __shared__ float ls[8];
    __shared__ float lc[8];
    if (sub == 0) {
        int slot = wave * 2 + half;
        ls[slot] = per_pt;
        lc[slot] = is_pos;
    }
    __syncthreads();
    if (threadIdx.x == 0) {
        double ssum = 0.0;
        float csum = 0.0f;
        #pragma unroll
        for (int k = 0; k < 8; ++k) {
            ssum += (double)ls[k];
            csum += lc[k];
        }
        partial[blockIdx.x] = ssum;     // distinct address per block
        pcnt[blockIdx.x] = csum;
    }
}

// ---------------------------------------------------------------------------
// K4: single-block reduction of the block partials -> final scalar loss.
// ---------------------------------------------------------------------------
__global__ void finalize_kernel(const double* __restrict__ partial,
                                const float* __restrict__ pcnt,
                                int n, float* __restrict__ out) {
    double s = 0.0, c = 0.0;
    for (int i = threadIdx.x; i < n; i += blockDim.x) {
        s += partial[i];
        c += (double)pcnt[i];
    }
    #pragma unroll
    for (int off = 32; off > 0; off >>= 1) {
        s += __shfl_down(s, off);
        c += __shfl_down(c, off);
    }
    __shared__ double ws_s[4];
    __shared__ double ws_c[4];
    int wave = threadIdx.x >> 6;
    int lane = threadIdx.x & 63;
    if (lane == 0) { ws_s[wave] = s; ws_c[wave] = c; }
    __syncthreads();
    if (threadIdx.x == 0) {
        double S = ws_s[0] + ws_s[1] + ws_s[2] + ws_s[3];
        double C = ws_c[0] + ws_c[1] + ws_c[2] + ws_c[3];
        out[0] = (float)(S / (C + 1e-7));
    }
}

extern "C" void kernel_launch(void* const* d_in, const int* in_sizes, int n_in,
                              void* d_out, int out_size, void* d_ws, size_t ws_size,
                              hipStream_t stream) {
    const float* pred    = (const float*)d_in[0];
    const float* h_state = (const float*)d_in[2];
    const int*   h_faces = (const int*)d_in[3];
    float* out = (float*)d_out;

    const int bs = 2;
    const int n_pred = in_sizes[0] / (bs * 3);   // 8192
    const int n_v    = in_sizes[2] / (bs * 6);   // 6890
    const int n_f    = in_sizes[3] / (bs * 3);   // 13776
    const int nq = bs * n_pred;                  // 16384
    const int nblk = (nq + 7) / 8;               // 2048 blocks, 8 queries each
    const int nfb  = (bs * n_f + 1023) / 1024;   // 27 face blocks @1024

    // ---- workspace layout (float-element offsets from d_ws) ----
    size_t o_svec    = 0;                                  // bs*n_v*3 (zeroed)
    size_t o_scnt    = o_svec + (size_t)bs * n_v * 3;      // bs*n_v   (zeroed)
    size_t o_zeroend = (o_scnt + (size_t)bs * n_v + 3) & ~(size_t)3;
    size_t o_cs      = o_zeroend;                          // bs*1001 i
    size_t o_partial = (o_cs + (size_t)bs * (NCELL + 1) + 1) & ~(size_t)1; // nblk d
    size_t o_pcnt    = o_partial + 2 * (size_t)nblk;       // nblk f
    size_t o_spk     = (o_pcnt + (size_t)nblk + 3) & ~(size_t)3;   // bs*n_v f4
    size_t o_vert    = o_spk + (size_t)bs * n_v * 4;               // bs*n_v*2 f4

    float* base = (float*)d_ws;
    float*  svec      = base + o_svec;
    float*  scnt      = base + o_scnt;
    int*    cellstart = (int*)(base + o_cs);
    double* partial   = (double*)(base + o_partial);
    float*  pcnt      = base + o_pcnt;
    float4* spk       = (float4*)(base + o_spk);
    float4* vert      = (float4*)(base + o_vert);

    hipMemsetAsync(d_ws, 0, o_zeroend * sizeof(float), stream);

    k_ab<<<nfb + bs, 1024, 0, stream>>>(
        h_state, h_faces, svec, scnt, cellstart, spk, n_v, n_f, bs, nfb);

    int nvb = (bs * n_v + 1023) / 1024;          // 14 normalize blocks @1024
    k2_normalize<<<nvb, 1024, 0, stream>>>(h_state, svec, scnt, vert, n_v, bs);

    k3_query<<<nblk, 256, 0, stream>>>(
        pred, vert, spk, cellstart, partial, pcnt, n_v, n_pred, bs);

    finalize_kernel<<<1, 256, 0, stream>>>(partial, pcnt, nblk, out);
}

// Round 8
// 99.895 us; speedup vs baseline: 1.2270x; 1.0990x over previous
//
#include <hip/hip_runtime.h>
#include <cstdint>
#include <climits>

#define EPSF 1e-7f
#define NCELL 1000          // 10x10x10 cells per batch, cell size 0.1 = radius
#define RPAD 0.10002f       // radius + fuzz for f32 binning boundary safety

// SESSION LESSONS (measured):
//  - prevR2: per-wave __threadfence = cache-wide wb -> +300us. Never fence.
//  - prevR6: same-address device atomics serialize cross-XCD (16k -> +70us).
//  - prevR10/R11: k3 block-level LDS retirement best; per-wave costs ~7us.
//  - R1: k1 per-face (3x fewer loads) neutral; file measured 101.11us. BEST.
//  - R2: k3 VGPR diet + launch_bounds(256,8) neutral -> not occupancy-capped.
//  - R3: spin-fusion + ticket/bucket tail = +21.5us (ticket ~ +18, R6 pattern).
//  - R4/R7 decomposition: lazy normals ~neutral; k_ab FUSION itself ~ +3.5us.
//    Mechanism: 330K face atomics concentrated into 27x1024 blocks (27 CUs)
//    vs 431x64 blocks spread over 256 CUs. Wide thin grids win for scatter
//    atomics.
//  - Model: ~80us of timed harness poison fills (256MB workspace re-poison,
//    ~80% HBM peak, not kernel-controllable) + ~20us attackable kernel time
//    that is insensitive to ~18 structural experiments across 2 sessions.
//  - THIS ROUND: full revert to the R1-measured best file (101.11us).

__device__ __forceinline__ int cell_of(float x, float y, float z) {
    int cx = min(max((int)(x * 10.0f), 0), 9);
    int cy = min(max((int)(y * 10.0f), 0), 9);
    int cz = min(max((int)(z * 10.0f), 0), 9);
    return (cx * 10 + cy) * 10 + cz;
}

// ---------------------------------------------------------------------------
// K1: one thread per FACE (normal computed once, 12 atomics) + per-vertex
// cell histogram on the low thread ids. 64-thread blocks -> max CU spread.
// ---------------------------------------------------------------------------
__global__ void k1_face_count(const float* __restrict__ hs,
                              const int* __restrict__ hf,
                              float* __restrict__ svec,
                              float* __restrict__ scnt,
                              int* __restrict__ counts,
                              int n_v, int n_f, int bs) {
    int t = blockIdx.x * blockDim.x + threadIdx.x;
    if (t < bs * n_f) {
        int b = t / n_f;
        int f = t - b * n_f;
        const int* fb = hf + (size_t)b * 3 * n_f;
        int i0 = fb[f];
        int i1 = fb[n_f + f];
        int i2 = fb[2 * n_f + f];
        const float* xs = hs + (size_t)b * 6 * n_v;
        const float* ys = xs + n_v;
        const float* zs = xs + 2 * n_v;
        float ax = xs[i0], ay = ys[i0], az = zs[i0];
        float bx = xs[i1], by = ys[i1], bz = zs[i1];
        float cx = xs[i2], cy = ys[i2], cz = zs[i2];
        float e1x = bx - ax, e1y = by - ay, e1z = bz - az;
        float e2x = cx - ax, e2y = cy - ay, e2z = cz - az;
        float fx = e1y * e2z - e1z * e2y;
        float fy = e1z * e2x - e1x * e2z;
        float fz = e1x * e2y - e1y * e2x;
        float nrm = sqrtf(fx * fx + fy * fy + fz * fz) + EPSF;
        fx /= nrm; fy /= nrm; fz /= nrm;
        float* sb = svec + (size_t)b * n_v * 3;
        float* cb = scnt + (size_t)b * n_v;
        atomicAdd(&sb[i0 * 3 + 0], fx);
        atomicAdd(&sb[i0 * 3 + 1], fy);
        atomicAdd(&sb[i0 * 3 + 2], fz);
        atomicAdd(&sb[i1 * 3 + 0], fx);
        atomicAdd(&sb[i1 * 3 + 1], fy);
        atomicAdd(&sb[i1 * 3 + 2], fz);
        atomicAdd(&sb[i2 * 3 + 0], fx);
        atomicAdd(&sb[i2 * 3 + 1], fy);
        atomicAdd(&sb[i2 * 3 + 2], fz);
        atomicAdd(&cb[i0], 1.0f);
        atomicAdd(&cb[i1], 1.0f);
        atomicAdd(&cb[i2], 1.0f);
    }
    if (t < bs * n_v) {
        int b = t / n_v;
        int v = t - b * n_v;
        const float* xs = hs + (size_t)b * 6 * n_v;
        float x = xs[v], y = xs[n_v + v], z = xs[2 * n_v + v];
        atomicAdd(&counts[b * NCELL + cell_of(x, y, z)], 1);
    }
}

// ---------------------------------------------------------------------------
// K2 (fused, 1024-thread blocks): normalize -> vert[]; per-batch scan +
// scatter.
// ---------------------------------------------------------------------------
__global__ void k2_build(const float* __restrict__ hs,
                         const float* __restrict__ svec,
                         const float* __restrict__ scnt,
                         const int* __restrict__ counts,
                         int* __restrict__ cellstart,
                         float4* __restrict__ vert,
                         float4* __restrict__ spk,
                         int n_v, int bs, int nvb) {
    __shared__ int cursor_l[NCELL];
    if (blockIdx.x < (unsigned)nvb) {
        int t = blockIdx.x * blockDim.x + threadIdx.x;
        if (t >= bs * n_v) return;
        int b = t / n_v;
        int v = t - b * n_v;
        float cc = scnt[t] + EPSF;
        float vx = svec[t * 3 + 0] / cc;
        float vy = svec[t * 3 + 1] / cc;
        float vz = svec[t * 3 + 2] / cc;
        float nrm = sqrtf(vx * vx + vy * vy + vz * vz) + EPSF;
        const float* xs = hs + (size_t)b * 6 * n_v;
        float x = xs[v], y = xs[n_v + v], z = xs[2 * n_v + v];
        vert[2 * (size_t)t + 0] = make_float4(x, y, z, 0.0f);
        vert[2 * (size_t)t + 1] = make_float4(vx / nrm, vy / nrm, vz / nrm, 0.0f);
        return;
    }
    int batch = blockIdx.x - nvb;
    if (threadIdx.x < 64) {
        int lane = threadIdx.x;
        int local[16];
        int mysum = 0;
        #pragma unroll
        for (int k = 0; k < 16; ++k) {
            int c = lane * 16 + k;
            int v = (c < NCELL) ? counts[batch * NCELL + c] : 0;
            local[k] = v;
            mysum += v;
        }
        int s = mysum;
        #pragma unroll
        for (int off = 1; off < 64; off <<= 1) {
            int n = __shfl_up(s, off);
            if (lane >= off) s += n;
        }
        int excl = s - mysum;
        #pragma unroll
        for (int k = 0; k < 16; ++k) {
            int c = lane * 16 + k;
            if (c < NCELL) {
                cellstart[batch * (NCELL + 1) + c] = excl;
                cursor_l[c] = excl;
                excl += local[k];
            }
        }
        if (lane == 63) cellstart[batch * (NCELL + 1) + NCELL] = s;
    }
    __syncthreads();
    const float* xs = hs + (size_t)batch * 6 * n_v;
    for (int v = threadIdx.x; v < n_v; v += blockDim.x) {
        float x = xs[v], y = xs[n_v + v], z = xs[2 * n_v + v];
        int cell = cell_of(x, y, z);
        int pos = atomicAdd(&cursor_l[cell], 1);
        spk[(size_t)batch * n_v + pos] = make_float4(x, y, z, __int_as_float(v));
    }
}

// ---------------------------------------------------------------------------
// K3: half-wave queries (one query per 32 lanes, 8192 waves) + eager
// round-0 candidate loads + BLOCK-LEVEL LDS retirement (measured best).
// ---------------------------------------------------------------------------
__global__ void k3_query(const float* __restrict__ pred,
                         const float4* __restrict__ vert,
                         const float4* __restrict__ spk,
                         const int* __restrict__ cellstart,
                         double* __restrict__ partial,
                         float* __restrict__ pcnt,
                         int n_v, int n_pred, int bs) {
    const int lane = threadIdx.x & 63;
    const int wave = threadIdx.x >> 6;
    const int sub = lane & 31;          // lane within half-wave
    const int half = lane >> 5;
    const int qid = blockIdx.x * 8 + wave * 2 + half;
    const int nq = bs * n_pred;

    float per_pt = 0.0f;
    float is_pos = 0.0f;

    if (qid < nq) {
        const int b = qid / n_pred;
        const float4* vb = vert + 2 * (size_t)b * n_v;
        const float4* sp = spk + (size_t)b * n_v;
        const int* csb = cellstart + b * (NCELL + 1);
        const float px = pred[(size_t)qid * 3 + 0];
        const float py = pred[(size_t)qid * 3 + 1];
        const float pz = pred[(size_t)qid * 3 + 2];

        int xlo = max(0, (int)floorf((px - RPAD) * 10.0f));
        int xhi = min(9, (int)floorf((px + RPAD) * 10.0f));
        int ylo = max(0, (int)floorf((py - RPAD) * 10.0f));
        int yhi = min(9, (int)floorf((py + RPAD) * 10.0f));
        int zlo = max(0, (int)floorf((pz - RPAD) * 10.0f));
        int zhi = min(9, (int)floorf((pz + RPAD) * 10.0f));

        int ip = min(sub, 8);
        int cxr = xlo + ip / 3;
        int cyr = ylo + ip % 3;
        bool validr = (cxr <= xhi) && (cyr <= yhi) && (sub < 9);
        int rowbase = (min(cxr, 9) * 10 + min(cyr, 9)) * 10;
        int rsv = csb[rowbase + zlo];
        int rev = csb[rowbase + zhi + 1];
        if (!validr) rev = rsv;         // empty run

        int RS[9], RE[9];
        #pragma unroll
        for (int i = 0; i < 9; ++i) {
            RS[i] = __shfl(rsv, i, 32);
            RE[i] = __shfl(rev, i, 32);
        }

        float4 c0[9];
        #pragma unroll
        for (int i = 0; i < 9; ++i) {
            int p = RS[i] + sub;
            c0[i] = sp[(p < RE[i]) ? p : 0];
        }

        int l0 = INT_MAX, l1 = INT_MAX, l2 = INT_MAX, l3 = INT_MAX;
        #pragma unroll
        for (int i = 0; i < 9; ++i) {
            if (RS[i] + sub < RE[i]) {
                float4 c4 = c0[i];
                float dx = px - c4.x;
                float dy = py - c4.y;
                float dz = pz - c4.z;
                float d2 = dx * dx + dy * dy + dz * dz;
                if (d2 < 0.01f) {           // 0.01f == f32(0.1*0.1)
                    int vid = __float_as_int(c4.w);
                    if (vid < l3) {
                        if (vid < l1) {
                            if (vid < l0) { l3 = l2; l2 = l1; l1 = l0; l0 = vid; }
                            else          { l3 = l2; l2 = l1; l1 = vid; }
                        } else {
                            if (vid < l2) { l3 = l2; l2 = vid; }
                            else          { l3 = vid; }
                        }
                    }
                }
            }
        }
        #pragma unroll
        for (int i = 0; i < 9; ++i) {
            for (int p = RS[i] + 32 + sub; p < RE[i]; p += 32) {
                float4 c4 = sp[p];
                float dx = px - c4.x;
                float dy = py - c4.y;
                float dz = pz - c4.z;
                float d2 = dx * dx + dy * dy + dz * dz;
                if (d2 < 0.01f) {
                    int vid = __float_as_int(c4.w);
                    if (vid < l3) {
                        if (vid < l1) {
                            if (vid < l0) { l3 = l2; l2 = l1; l1 = l0; l0 = vid; }
                            else          { l3 = l2; l2 = l1; l1 = vid; }
                        } else {
                            if (vid < l2) { l3 = l2; l2 = vid; }
                            else          { l3 = vid; }
                        }
                    }
                }
            }
        }

        #pragma unroll
        for (int off = 1; off < 32; off <<= 1) {
            int r0 = __shfl_xor(l3, off);
            int r1 = __shfl_xor(l2, off);
            int r2 = __shfl_xor(l1, off);
            int r3 = __shfl_xor(l0, off);
            int m0 = min(l0, r0);
            int m1 = min(l1, r1);
            int m2 = min(l2, r2);
            int m3 = min(l3, r3);
            int t0 = min(m0, m2), t2 = max(m0, m2);
            int t1 = min(m1, m3), t3 = max(m1, m3);
            l0 = min(t0, t1); l1 = max(t0, t1);
            l2 = min(t2, t3); l3 = max(t2, t3);
        }

        int id0 = (l0 == INT_MAX) ? 0 : l0;      // no hits -> index 0
        int id1 = (l1 == INT_MAX) ? id0 : l1;    // unfilled -> first hit
        int id2 = (l2 == INT_MAX) ? id0 : l2;
        int id3 = (l3 == INT_MAX) ? id0 : l3;
        int ids[4] = {id0, id1, id2, id3};

        float vd[4];
        float cm = 0.0f;
        #pragma unroll
        for (int j = 0; j < 4; ++j) {
            int id = ids[j];
            float4 cj = vb[2 * id + 0];
            float4 nj = vb[2 * id + 1];
            float dx = px - cj.x;
            float dy = py - cj.y;
            float dz = pz - cj.z;
            float dot = dx * nj.x + dy * nj.y + dz * nj.z;
            float w = (dot >= -0.1f) ? 1.0f : 0.0f;
            float v = (dot - 0.001f) * w;
            bool msk = v < 0.0f;
            vd[j] = msk ? v : 0.0f;
            cm += msk ? 1.0f : 0.0f;
        }
        float s = ((vd[0] + vd[1]) + vd[2]) + vd[3];
        float a = s / (cm + EPSF);
        per_pt = a * a;
        is_pos = (per_pt > 0.0f) ? 1.0f : 0.0f;
    }

    __shared__ float ls[8];
    __shared__ float lc[8];
    if (sub == 0) {
        int slot = wave * 2 + half;
        ls[slot] = per_pt;
        lc[slot] = is_pos;
    }
    __syncthreads();
    if (threadIdx.x == 0) {
        double ssum = 0.0;
        float csum = 0.0f;
        #pragma unroll
        for (int k = 0; k < 8; ++k) {
            ssum += (double)ls[k];
            csum += lc[k];
        }
        partial[blockIdx.x] = ssum;     // distinct address per block
        pcnt[blockIdx.x] = csum;
    }
}

// ---------------------------------------------------------------------------
// K4: single-block reduction of the block partials -> final scalar loss.
// ---------------------------------------------------------------------------
__global__ void finalize_kernel(const double* __restrict__ partial,
                                const float* __restrict__ pcnt,
                                int n, float* __restrict__ out) {
    double s = 0.0, c = 0.0;
    for (int i = threadIdx.x; i < n; i += blockDim.x) {
        s += partial[i];
        c += (double)pcnt[i];
    }
    #pragma unroll
    for (int off = 32; off > 0; off >>= 1) {
        s += __shfl_down(s, off);
        c += __shfl_down(c, off);
    }
    __shared__ double ws_s[4];
    __shared__ double ws_c[4];
    int wave = threadIdx.x >> 6;
    int lane = threadIdx.x & 63;
    if (lane == 0) { ws_s[wave] = s; ws_c[wave] = c; }
    __syncthreads();
    if (threadIdx.x == 0) {
        double S = ws_s[0] + ws_s[1] + ws_s[2] + ws_s[3];
        double C = ws_c[0] + ws_c[1] + ws_c[2] + ws_c[3];
        out[0] = (float)(S / (C + 1e-7));
    }
}

extern "C" void kernel_launch(void* const* d_in, const int* in_sizes, int n_in,
                              void* d_out, int out_size, void* d_ws, size_t ws_size,
                              hipStream_t stream) {
    const float* pred    = (const float*)d_in[0];
    const float* h_state = (const float*)d_in[2];
    const int*   h_faces = (const int*)d_in[3];
    float* out = (float*)d_out;

    const int bs = 2;
    const int n_pred = in_sizes[0] / (bs * 3);   // 8192
    const int n_v    = in_sizes[2] / (bs * 6);   // 6890
    const int n_f    = in_sizes[3] / (bs * 3);   // 13776
    const int nq = bs * n_pred;                  // 16384
    const int nblk = (nq + 7) / 8;               // 2048 blocks, 8 queries each

    // ---- workspace layout (float-element offsets from d_ws) ----
    size_t o_svec    = 0;                                  // bs*n_v*3 (zeroed)
    size_t o_scnt    = o_svec + (size_t)bs * n_v * 3;      // bs*n_v   (zeroed)
    size_t o_counts  = o_scnt + (size_t)bs * n_v;          // bs*1000 i (zeroed)
    size_t o_zeroend = (o_counts + (size_t)bs * NCELL + 3) & ~(size_t)3;
    size_t o_cs      = o_zeroend;                          // bs*1001 i
    size_t o_partial = (o_cs + (size_t)bs * (NCELL + 1) + 1) & ~(size_t)1; // nblk d
    size_t o_pcnt    = o_partial + 2 * (size_t)nblk;       // nblk f
    size_t o_spk     = (o_pcnt + (size_t)nblk + 3) & ~(size_t)3;   // bs*n_v f4
    size_t o_vert    = o_spk + (size_t)bs * n_v * 4;               // bs*n_v*2 f4

    float* base = (float*)d_ws;
    float*  svec      = base + o_svec;
    float*  scnt      = base + o_scnt;
    int*    counts    = (int*)(base + o_counts);
    int*    cellstart = (int*)(base + o_cs);
    double* partial   = (double*)(base + o_partial);
    float*  pcnt      = base + o_pcnt;
    float4* spk       = (float4*)(base + o_spk);
    float4* vert      = (float4*)(base + o_vert);

    hipMemsetAsync(d_ws, 0, o_zeroend * sizeof(float), stream);

    int t1 = bs * n_f;   // one thread per FACE; bs*n_f (27552) >= bs*n_v (13780)
    k1_face_count<<<(t1 + 63) / 64, 64, 0, stream>>>(
        h_state, h_faces, svec, scnt, counts, n_v, n_f, bs);

    int nvb = (bs * n_v + 1023) / 1024;          // 14 normalize blocks @1024
    k2_build<<<nvb + bs, 1024, 0, stream>>>(
        h_state, svec, scnt, counts, cellstart, vert, spk, n_v, bs, nvb);

    k3_query<<<nblk, 256, 0, stream>>>(
        pred, vert, spk, cellstart, partial, pcnt, n_v, n_pred, bs);

    finalize_kernel<<<1, 256, 0, stream>>>(partial, pcnt, nblk, out);
}